// Round 2
// baseline (1160.529 us; speedup 1.0000x reference)
//
#include <hip/hip_runtime.h>
#include <hip/hip_bf16.h>

// ---------- int-width-agnostic index load (w64=1 -> int64 data on device) ----------
__device__ __forceinline__ int gidx(const void* p, long long i, int w64) {
    if (w64) return (int)((const long long*)p)[i];
    return ((const int*)p)[i];
}

// Detect whether integer inputs are int64 (odd int32 words all zero) or int32.
__global__ void detect_kernel(const int* __restrict__ edge_words, int* __restrict__ flag, int E) {
    __shared__ int anyNZ;
    if (threadIdx.x == 0) anyNZ = 0;
    __syncthreads();
    const long long totalWords = 2LL * E;  // int32 words if data is int32; halves if int64
    const long long step = totalWords / 1024;
    int nz = 0;
    for (int i = 0; i < 4; ++i) {
        long long w = ((long long)(threadIdx.x * 4 + i) * step) | 1;
        if (w < totalWords) nz |= edge_words[w];
    }
    if (nz) atomicOr(&anyNZ, 1);
    __syncthreads();
    if (threadIdx.x == 0) flag[0] = anyNZ ? 0 : 1;
}

// ---------- CSR build ----------
__global__ void hist_kernel(const void* __restrict__ edge, const int* __restrict__ flag,
                            int* __restrict__ deg, int E, int n) {
    int e = blockIdx.x * 256 + threadIdx.x;
    if (e < E) {
        int d = gidx(edge, (long long)E + e, flag[0]);
        if ((unsigned)d < (unsigned)n) atomicAdd(&deg[d], 1);
    }
}

// in-place exclusive scan over offs[0..n-1]; 2048 elems / block
__global__ void scanA(int* __restrict__ offs, int* __restrict__ blockSums, int n) {
    __shared__ int ts[256];
    const int ITEMS = 8;
    int base = blockIdx.x * 2048 + threadIdx.x * ITEMS;
    int v[ITEMS];
    int sum = 0;
#pragma unroll
    for (int i = 0; i < ITEMS; ++i) {
        int idx = base + i;
        v[i] = (idx < n) ? offs[idx] : 0;
        sum += v[i];
    }
    ts[threadIdx.x] = sum;
    __syncthreads();
    int incl = sum;
    for (int d = 1; d < 256; d <<= 1) {
        int y = 0;
        if (threadIdx.x >= (unsigned)d) y = ts[threadIdx.x - d];
        __syncthreads();
        incl += y;
        ts[threadIdx.x] = incl;
        __syncthreads();
    }
    int run = incl - sum;
#pragma unroll
    for (int i = 0; i < ITEMS; ++i) {
        int idx = base + i;
        if (idx < n) offs[idx] = run;
        run += v[i];
    }
    if (threadIdx.x == 255) blockSums[blockIdx.x] = incl;
}

__global__ void scanB(int* __restrict__ blockSums, int nb) {
    __shared__ int ts[256];
    int t = threadIdx.x;
    int v = (t < nb) ? blockSums[t] : 0;
    ts[t] = v;
    __syncthreads();
    int incl = v;
    for (int d = 1; d < 256; d <<= 1) {
        int y = 0;
        if (t >= d) y = ts[t - d];
        __syncthreads();
        incl += y;
        ts[t] = incl;
        __syncthreads();
    }
    if (t < nb) blockSums[t] = incl - v;
}

__global__ void scanC(int* __restrict__ offs, const int* __restrict__ blockSums, int n, int total) {
    int base = blockIdx.x * 2048 + threadIdx.x * 8;
    int add = blockSums[blockIdx.x];
#pragma unroll
    for (int i = 0; i < 8; ++i) {
        int idx = base + i;
        if (idx < n) offs[idx] += add;
    }
    if (blockIdx.x == 0 && threadIdx.x == 0) offs[n] = total;
}

__global__ void scatter_kernel(const void* __restrict__ edge, const int* __restrict__ flag,
                               const int* __restrict__ offs, int* __restrict__ cursor,
                               int* __restrict__ ss, int E, int n) {
    int e = blockIdx.x * 256 + threadIdx.x;
    if (e < E) {
        int w64 = flag[0];
        int d = gidx(edge, (long long)E + e, w64);
        int s = gidx(edge, e, w64);
        if ((unsigned)d < (unsigned)n) {
            if ((unsigned)s >= (unsigned)n) s = 0;
            int p = offs[d] + atomicAdd(&cursor[d], 1);
            ss[p] = s;
        }
    }
}

// ---------- dense per-node matmuls: Z = X@Wl, R = X@Wr + b ----------
__global__ void __launch_bounds__(256) mm_kernel(const float* __restrict__ X,
                                                 const float* __restrict__ Wl,
                                                 const float* __restrict__ Wr,
                                                 const float* __restrict__ Bv,
                                                 float* __restrict__ Z,
                                                 float* __restrict__ R, int n) {
    __shared__ float2 wlr[4096];  // [k][c] -> (Wl, Wr)
    __shared__ float bs[64];
    for (int i = threadIdx.x; i < 4096; i += 256)
        wlr[i] = make_float2(Wl[i], Wr[i]);
    if (threadIdx.x < 64) bs[threadIdx.x] = Bv[threadIdx.x];
    __syncthreads();
    const int lane = threadIdx.x & 63;
    int node = (blockIdx.x << 2) | (threadIdx.x >> 6);
    const int stride = gridDim.x << 2;
    for (; node < n; node += stride) {
        float xv = X[node * 64 + lane];
        float az = 0.f, ar = bs[lane];
#pragma unroll
        for (int k = 0; k < 64; ++k) {
            float a = __shfl(xv, k, 64);
            float2 w = wlr[k * 64 + lane];
            az += a * w.x;
            ar += a * w.y;
        }
        Z[node * 64 + lane] = az;
        R[node * 64 + lane] = ar;
    }
}

// ---------- CSR aggregation + epilogue: H = relu(mean_agg(Z) + R) ----------
__global__ void __launch_bounds__(256) agg_kernel(const float* __restrict__ Z,
                                                  const float* __restrict__ R,
                                                  const int* __restrict__ offs,
                                                  const int* __restrict__ ss,
                                                  float* __restrict__ H, int n) {
    const int lane = threadIdx.x & 63;
    const int node = (blockIdx.x << 2) | (threadIdx.x >> 6);
    if (node >= n) return;
    const int off = offs[node], end = offs[node + 1];
    float acc = 0.f;
    for (int k = off; k < end; ++k) {
        int s = ss[k];
        if ((unsigned)s < (unsigned)n) acc += Z[s * 64 + lane];
    }
    const int deg = end - off;
    float v = (deg > 0 ? acc / (float)deg : 0.f) + R[node * 64 + lane];
    H[node * 64 + lane] = v > 0.f ? v : 0.f;
}

// ---------- global mean pool (batch sorted): per-block running sums ----------
__global__ void pool_kernel(const float* __restrict__ H, const void* __restrict__ batch,
                            const int* __restrict__ flag, float* __restrict__ pool, int n) {
    const int lane = threadIdx.x;  // 64 threads
    int start = blockIdx.x * 512;
    int end = min(start + 512, n);
    if (start >= end) return;
    const int w64 = flag[0];
    float acc = 0.f;
    int cur = gidx(batch, start, w64) & 63;
    for (int i = start; i < end; ++i) {
        int g = gidx(batch, i, w64) & 63;
        if (g != cur) {
            atomicAdd(&pool[cur * 64 + lane], acc);
            acc = 0.f;
            cur = g;
        }
        acc += H[i * 64 + lane];
    }
    atomicAdd(&pool[cur * 64 + lane], acc);
}

// ---------- head MLP: out = relu(g@Wc1+bc1)@Wc2 + bc2 ----------
__global__ void head_kernel(const float* __restrict__ pool, const void* __restrict__ batch,
                            const int* __restrict__ flag,
                            const float* __restrict__ Wc1, const float* __restrict__ bc1,
                            const float* __restrict__ Wc2, const float* __restrict__ bc2,
                            float* __restrict__ out, int n) {
    __shared__ float gm[64 * 64];
    __shared__ float am[64 * 32];
    __shared__ int cnts[64];
    const int tid = threadIdx.x;  // 256
    const int w64 = flag[0];
    if (tid < 64) {
        int lo = 0, hi = n;
        while (lo < hi) { int mid = (lo + hi) >> 1; if (gidx(batch, mid, w64) < tid) lo = mid + 1; else hi = mid; }
        int lo2 = 0, hi2 = n;
        int v2 = tid + 1;
        while (lo2 < hi2) { int mid = (lo2 + hi2) >> 1; if (gidx(batch, mid, w64) < v2) lo2 = mid + 1; else hi2 = mid; }
        cnts[tid] = lo2 - lo;
    }
    __syncthreads();
    for (int i = tid; i < 4096; i += 256) {
        int g = i >> 6;
        float c = (float)(cnts[g] > 0 ? cnts[g] : 1);
        gm[i] = pool[i] / c;
    }
    __syncthreads();
    for (int i = tid; i < 64 * 32; i += 256) {
        int g = i >> 5, j = i & 31;
        float acc = bc1[j];
        for (int k = 0; k < 64; ++k) acc += gm[g * 64 + k] * Wc1[k * 32 + j];
        am[i] = acc > 0.f ? acc : 0.f;
    }
    __syncthreads();
    if (tid < 128) {
        int g = tid >> 1, o = tid & 1;
        float acc = bc2[o];
        for (int j = 0; j < 32; ++j) acc += am[g * 32 + j] * Wc2[j * 2 + o];
        out[tid] = acc;
    }
}

extern "C" void kernel_launch(void* const* d_in, const int* in_sizes, int n_in,
                              void* d_out, int out_size, void* d_ws, size_t ws_size,
                              hipStream_t stream) {
    const float* x        = (const float*)d_in[0];
    const void* edge      = d_in[1];     // int32 or int64, auto-detected
    const void* batch     = d_in[2];
    const float* W1l = (const float*)d_in[3];
    const float* b1  = (const float*)d_in[4];
    const float* W1r = (const float*)d_in[5];
    const float* W2l = (const float*)d_in[6];
    const float* b2  = (const float*)d_in[7];
    const float* W2r = (const float*)d_in[8];
    const float* W3l = (const float*)d_in[9];
    const float* b3  = (const float*)d_in[10];
    const float* W3r = (const float*)d_in[11];
    const float* Wc1 = (const float*)d_in[12];
    const float* bc1 = (const float*)d_in[13];
    const float* Wc2 = (const float*)d_in[14];
    const float* bc2 = (const float*)d_in[15];

    const int n = in_sizes[0] / 64;   // 100000
    const int E = in_sizes[1] / 2;    // 1600000

    // workspace layout (512B aligned chunks)
    char* w = (char*)d_ws;
    size_t o = 0;
    auto take = [&](size_t bytes) -> void* {
        void* p = w + o;
        o = (o + bytes + 511) & ~(size_t)511;
        return p;
    };
    int* flag      = (int*)take(sizeof(int));
    int* offs      = (int*)take((size_t)(n + 1) * sizeof(int));
    int* cursor    = (int*)take((size_t)n * sizeof(int));
    int* blockSums = (int*)take(256 * sizeof(int));
    int* ss        = (int*)take((size_t)E * sizeof(int));
    float* Z       = (float*)take((size_t)n * 64 * sizeof(float));
    float* R       = (float*)take((size_t)n * 64 * sizeof(float));
    float* HA      = (float*)take((size_t)n * 64 * sizeof(float));
    float* HB      = (float*)take((size_t)n * 64 * sizeof(float));
    float* pool    = (float*)take(64 * 64 * sizeof(float));

    hipMemsetAsync(offs, 0, (size_t)(n + 1) * sizeof(int), stream);
    hipMemsetAsync(cursor, 0, (size_t)n * sizeof(int), stream);
    hipMemsetAsync(pool, 0, 64 * 64 * sizeof(float), stream);

    detect_kernel<<<1, 256, 0, stream>>>((const int*)edge, flag, E);

    // CSR build (reused by all 3 layers)
    hist_kernel<<<(E + 255) / 256, 256, 0, stream>>>(edge, flag, offs, E, n);
    const int nbScan = (n + 2047) / 2048;
    scanA<<<nbScan, 256, 0, stream>>>(offs, blockSums, n);
    scanB<<<1, 256, 0, stream>>>(blockSums, nbScan);
    scanC<<<nbScan, 256, 0, stream>>>(offs, blockSums, n, E);
    scatter_kernel<<<(E + 255) / 256, 256, 0, stream>>>(edge, flag, offs, cursor, ss, E, n);

    const int aggBlocks = (n + 3) / 4;
    // layer 1
    mm_kernel<<<1024, 256, 0, stream>>>(x, W1l, W1r, b1, Z, R, n);
    agg_kernel<<<aggBlocks, 256, 0, stream>>>(Z, R, offs, ss, HA, n);
    // layer 2
    mm_kernel<<<1024, 256, 0, stream>>>(HA, W2l, W2r, b2, Z, R, n);
    agg_kernel<<<aggBlocks, 256, 0, stream>>>(Z, R, offs, ss, HB, n);
    // layer 3
    mm_kernel<<<1024, 256, 0, stream>>>(HB, W3l, W3r, b3, Z, R, n);
    agg_kernel<<<aggBlocks, 256, 0, stream>>>(Z, R, offs, ss, HA, n);

    // pool + head
    pool_kernel<<<(n + 511) / 512, 64, 0, stream>>>(HA, batch, flag, pool, n);
    head_kernel<<<1, 256, 0, stream>>>(pool, batch, flag, Wc1, bc1, Wc2, bc2,
                                       (float*)d_out, n);
}

// Round 3
// 935.270 us; speedup vs baseline: 1.2408x; 1.2408x over previous
//
#include <hip/hip_runtime.h>
#include <hip/hip_bf16.h>

// ---------- int-width-agnostic index load (w64=1 -> int64 data on device) ----------
__device__ __forceinline__ int gidx(const void* p, long long i, int w64) {
    if (w64) return (int)((const long long*)p)[i];
    return ((const int*)p)[i];
}

__device__ __forceinline__ float bf2f(unsigned short u) {
    union { unsigned int ui; float f; } c;
    c.ui = ((unsigned int)u) << 16;
    return c.f;
}
__device__ __forceinline__ unsigned short f2bf(float f) {
    return (unsigned short)(__bfloat16_as_ushort(__float2bfloat16(f)));
}

// Detect whether integer inputs are int64 (odd int32 words all zero) or int32.
__global__ void detect_kernel(const int* __restrict__ edge_words, int* __restrict__ flag, int E) {
    __shared__ int anyNZ;
    if (threadIdx.x == 0) anyNZ = 0;
    __syncthreads();
    const long long totalWords = 2LL * E;
    const long long step = totalWords / 1024;
    int nz = 0;
    for (int i = 0; i < 4; ++i) {
        long long w = ((long long)(threadIdx.x * 4 + i) * step) | 1;
        if (w < totalWords) nz |= edge_words[w];
    }
    if (nz) atomicOr(&anyNZ, 1);
    __syncthreads();
    if (threadIdx.x == 0) flag[0] = anyNZ ? 0 : 1;
}

// ---------- zero-init scratch (replaces 3 hipMemsetAsync dispatches) ----------
__global__ void init_kernel(int* __restrict__ offs, int* __restrict__ cursor,
                            float* __restrict__ pool, int n) {
    int i = blockIdx.x * 256 + threadIdx.x;
    if (i <= n) offs[i] = 0;
    if (i < n) cursor[i] = 0;
    if (i < 4096) pool[i] = 0.f;
}

// ---------- CSR build ----------
__global__ void hist_kernel(const void* __restrict__ edge, const int* __restrict__ flag,
                            int* __restrict__ deg, int E, int n) {
    int e = blockIdx.x * 256 + threadIdx.x;
    if (e < E) {
        int d = gidx(edge, (long long)E + e, flag[0]);
        if ((unsigned)d < (unsigned)n) atomicAdd(&deg[d], 1);
    }
}

__global__ void scanA(int* __restrict__ offs, int* __restrict__ blockSums, int n) {
    __shared__ int ts[256];
    const int ITEMS = 8;
    int base = blockIdx.x * 2048 + threadIdx.x * ITEMS;
    int v[ITEMS];
    int sum = 0;
#pragma unroll
    for (int i = 0; i < ITEMS; ++i) {
        int idx = base + i;
        v[i] = (idx < n) ? offs[idx] : 0;
        sum += v[i];
    }
    ts[threadIdx.x] = sum;
    __syncthreads();
    int incl = sum;
    for (int d = 1; d < 256; d <<= 1) {
        int y = 0;
        if (threadIdx.x >= (unsigned)d) y = ts[threadIdx.x - d];
        __syncthreads();
        incl += y;
        ts[threadIdx.x] = incl;
        __syncthreads();
    }
    int run = incl - sum;
#pragma unroll
    for (int i = 0; i < ITEMS; ++i) {
        int idx = base + i;
        if (idx < n) offs[idx] = run;
        run += v[i];
    }
    if (threadIdx.x == 255) blockSums[blockIdx.x] = incl;
}

__global__ void scanB(int* __restrict__ blockSums, int nb) {
    __shared__ int ts[256];
    int t = threadIdx.x;
    int v = (t < nb) ? blockSums[t] : 0;
    ts[t] = v;
    __syncthreads();
    int incl = v;
    for (int d = 1; d < 256; d <<= 1) {
        int y = 0;
        if (t >= d) y = ts[t - d];
        __syncthreads();
        incl += y;
        ts[t] = incl;
        __syncthreads();
    }
    if (t < nb) blockSums[t] = incl - v;
}

__global__ void scanC(int* __restrict__ offs, const int* __restrict__ blockSums, int n, int total) {
    int base = blockIdx.x * 2048 + threadIdx.x * 8;
    int add = blockSums[blockIdx.x];
#pragma unroll
    for (int i = 0; i < 8; ++i) {
        int idx = base + i;
        if (idx < n) offs[idx] += add;
    }
    if (blockIdx.x == 0 && threadIdx.x == 0) offs[n] = total;
}

__global__ void scatter_kernel(const void* __restrict__ edge, const int* __restrict__ flag,
                               const int* __restrict__ offs, int* __restrict__ cursor,
                               int* __restrict__ ss, int E, int n) {
    int e = blockIdx.x * 256 + threadIdx.x;
    if (e < E) {
        int w64 = flag[0];
        int d = gidx(edge, (long long)E + e, w64);
        int s = gidx(edge, e, w64);
        if ((unsigned)d < (unsigned)n) {
            if ((unsigned)s >= (unsigned)n) s = 0;
            int p = offs[d] + atomicAdd(&cursor[d], 1);
            ss[p] = s;
        }
    }
}

// ---------- layer-1 dense matmuls: Z = X@Wl (bf16), R = X@Wr + b (f32) ----------
__global__ void __launch_bounds__(256) mm_kernel(const float* __restrict__ X,
                                                 const float* __restrict__ Wl,
                                                 const float* __restrict__ Wr,
                                                 const float* __restrict__ Bv,
                                                 unsigned short* __restrict__ Z,
                                                 float* __restrict__ R, int n) {
    __shared__ float2 wlr[4096];  // [k][c] -> (Wl, Wr)
    __shared__ float bs[64];
    for (int i = threadIdx.x; i < 4096; i += 256)
        wlr[i] = make_float2(Wl[i], Wr[i]);
    if (threadIdx.x < 64) bs[threadIdx.x] = Bv[threadIdx.x];
    __syncthreads();
    const int lane = threadIdx.x & 63;
    int node = (blockIdx.x << 2) | (threadIdx.x >> 6);
    const int stride = gridDim.x << 2;
    for (; node < n; node += stride) {
        float xv = X[node * 64 + lane];
        float az = 0.f, ar = bs[lane];
#pragma unroll
        for (int k = 0; k < 64; ++k) {
            float a = __shfl(xv, k, 64);
            float2 w = wlr[k * 64 + lane];
            az += a * w.x;
            ar += a * w.y;
        }
        Z[node * 64 + lane] = f2bf(az);
        R[node * 64 + lane] = ar;
    }
}

// ---------- gather-mean core: batched 8-deep neighbor loads ----------
__device__ __forceinline__ float gather_mean(const unsigned short* __restrict__ Zin,
                                             const int* __restrict__ ss,
                                             int off, int end, int lane) {
    float acc = 0.f;
    int k = off;
    for (; k + 8 <= end; k += 8) {
        int s0 = ss[k + 0], s1 = ss[k + 1], s2 = ss[k + 2], s3 = ss[k + 3];
        int s4 = ss[k + 4], s5 = ss[k + 5], s6 = ss[k + 6], s7 = ss[k + 7];
        float a0 = bf2f(Zin[(long long)s0 * 64 + lane]);
        float a1 = bf2f(Zin[(long long)s1 * 64 + lane]);
        float a2 = bf2f(Zin[(long long)s2 * 64 + lane]);
        float a3 = bf2f(Zin[(long long)s3 * 64 + lane]);
        float a4 = bf2f(Zin[(long long)s4 * 64 + lane]);
        float a5 = bf2f(Zin[(long long)s5 * 64 + lane]);
        float a6 = bf2f(Zin[(long long)s6 * 64 + lane]);
        float a7 = bf2f(Zin[(long long)s7 * 64 + lane]);
        acc += ((a0 + a1) + (a2 + a3)) + ((a4 + a5) + (a6 + a7));
    }
    for (; k < end; ++k) acc += bf2f(Zin[(long long)ss[k] * 64 + lane]);
    int deg = end - off;
    return deg > 0 ? acc / (float)deg : 0.f;
}

// ---------- fused: h = relu(mean + R); Zout = h@Wl (bf16); Rout = h@Wr + b ----------
__global__ void __launch_bounds__(256) aggmm_kernel(const unsigned short* __restrict__ Zin,
                                                    const float* __restrict__ Rin,
                                                    const int* __restrict__ offs,
                                                    const int* __restrict__ ss,
                                                    const float* __restrict__ Wl,
                                                    const float* __restrict__ Wr,
                                                    const float* __restrict__ Bv,
                                                    unsigned short* __restrict__ Zout,
                                                    float* __restrict__ Rout, int n) {
    __shared__ float2 wlr[4096];
    __shared__ float bs[64];
    for (int i = threadIdx.x; i < 4096; i += 256)
        wlr[i] = make_float2(Wl[i], Wr[i]);
    if (threadIdx.x < 64) bs[threadIdx.x] = Bv[threadIdx.x];
    __syncthreads();
    const int lane = threadIdx.x & 63;
    const int node = (blockIdx.x << 2) | (threadIdx.x >> 6);
    if (node >= n) return;
    const int off = offs[node], end = offs[node + 1];
    float h = gather_mean(Zin, ss, off, end, lane) + Rin[node * 64 + lane];
    h = h > 0.f ? h : 0.f;
    float az = 0.f, ar = bs[lane];
#pragma unroll
    for (int k = 0; k < 64; ++k) {
        float a = __shfl(h, k, 64);
        float2 w = wlr[k * 64 + lane];
        az += a * w.x;
        ar += a * w.y;
    }
    Zout[node * 64 + lane] = f2bf(az);
    Rout[node * 64 + lane] = ar;
}

// ---------- final layer: H = relu(mean + R) ----------
__global__ void __launch_bounds__(256) agg_kernel(const unsigned short* __restrict__ Zin,
                                                  const float* __restrict__ Rin,
                                                  const int* __restrict__ offs,
                                                  const int* __restrict__ ss,
                                                  float* __restrict__ H, int n) {
    const int lane = threadIdx.x & 63;
    const int node = (blockIdx.x << 2) | (threadIdx.x >> 6);
    if (node >= n) return;
    const int off = offs[node], end = offs[node + 1];
    float v = gather_mean(Zin, ss, off, end, lane) + Rin[node * 64 + lane];
    H[node * 64 + lane] = v > 0.f ? v : 0.f;
}

// ---------- global mean pool (batch sorted): 4 waves/block, 256 rows/wave ----------
__global__ void pool_kernel(const float* __restrict__ H, const void* __restrict__ batch,
                            const int* __restrict__ flag, float* __restrict__ pool, int n) {
    const int lane = threadIdx.x & 63;
    const int wave = threadIdx.x >> 6;
    int start = (blockIdx.x * 4 + wave) * 256;
    int end = min(start + 256, n);
    if (start >= end) return;
    const int w64 = flag[0];
    float acc = 0.f;
    int cur = gidx(batch, start, w64) & 63;
    for (int i = start; i < end; ++i) {
        int g = gidx(batch, i, w64) & 63;
        if (g != cur) {
            atomicAdd(&pool[cur * 64 + lane], acc);
            acc = 0.f;
            cur = g;
        }
        acc += H[i * 64 + lane];
    }
    atomicAdd(&pool[cur * 64 + lane], acc);
}

// ---------- head MLP: out = relu(g@Wc1+bc1)@Wc2 + bc2 ----------
__global__ void head_kernel(const float* __restrict__ pool, const void* __restrict__ batch,
                            const int* __restrict__ flag,
                            const float* __restrict__ Wc1, const float* __restrict__ bc1,
                            const float* __restrict__ Wc2, const float* __restrict__ bc2,
                            float* __restrict__ out, int n) {
    __shared__ float gm[64 * 64];
    __shared__ float am[64 * 32];
    __shared__ int cnts[64];
    const int tid = threadIdx.x;  // 256
    const int w64 = flag[0];
    if (tid < 64) {
        int lo = 0, hi = n;
        while (lo < hi) { int mid = (lo + hi) >> 1; if (gidx(batch, mid, w64) < tid) lo = mid + 1; else hi = mid; }
        int lo2 = 0, hi2 = n;
        int v2 = tid + 1;
        while (lo2 < hi2) { int mid = (lo2 + hi2) >> 1; if (gidx(batch, mid, w64) < v2) lo2 = mid + 1; else hi2 = mid; }
        cnts[tid] = lo2 - lo;
    }
    __syncthreads();
    for (int i = tid; i < 4096; i += 256) {
        int g = i >> 6;
        float c = (float)(cnts[g] > 0 ? cnts[g] : 1);
        gm[i] = pool[i] / c;
    }
    __syncthreads();
    for (int i = tid; i < 64 * 32; i += 256) {
        int g = i >> 5, j = i & 31;
        float acc = bc1[j];
        for (int k = 0; k < 64; ++k) acc += gm[g * 64 + k] * Wc1[k * 32 + j];
        am[i] = acc > 0.f ? acc : 0.f;
    }
    __syncthreads();
    if (tid < 128) {
        int g = tid >> 1, o = tid & 1;
        float acc = bc2[o];
        for (int j = 0; j < 32; ++j) acc += am[g * 32 + j] * Wc2[j * 2 + o];
        out[tid] = acc;
    }
}

extern "C" void kernel_launch(void* const* d_in, const int* in_sizes, int n_in,
                              void* d_out, int out_size, void* d_ws, size_t ws_size,
                              hipStream_t stream) {
    const float* x   = (const float*)d_in[0];
    const void* edge = d_in[1];     // int32 or int64, auto-detected
    const void* batch = d_in[2];
    const float* W1l = (const float*)d_in[3];
    const float* b1  = (const float*)d_in[4];
    const float* W1r = (const float*)d_in[5];
    const float* W2l = (const float*)d_in[6];
    const float* b2  = (const float*)d_in[7];
    const float* W2r = (const float*)d_in[8];
    const float* W3l = (const float*)d_in[9];
    const float* b3  = (const float*)d_in[10];
    const float* W3r = (const float*)d_in[11];
    const float* Wc1 = (const float*)d_in[12];
    const float* bc1 = (const float*)d_in[13];
    const float* Wc2 = (const float*)d_in[14];
    const float* bc2 = (const float*)d_in[15];

    const int n = in_sizes[0] / 64;   // 100000
    const int E = in_sizes[1] / 2;    // 1600000

    char* w = (char*)d_ws;
    size_t o = 0;
    auto take = [&](size_t bytes) -> void* {
        void* p = w + o;
        o = (o + bytes + 511) & ~(size_t)511;
        return p;
    };
    int* flag      = (int*)take(sizeof(int));
    int* offs      = (int*)take((size_t)(n + 1) * sizeof(int));
    int* cursor    = (int*)take((size_t)n * sizeof(int));
    int* blockSums = (int*)take(256 * sizeof(int));
    int* ss        = (int*)take((size_t)E * sizeof(int));
    unsigned short* ZA = (unsigned short*)take((size_t)n * 64 * sizeof(unsigned short));
    unsigned short* ZB = (unsigned short*)take((size_t)n * 64 * sizeof(unsigned short));
    float* RA      = (float*)take((size_t)n * 64 * sizeof(float));
    float* RB      = (float*)take((size_t)n * 64 * sizeof(float));
    float* H       = (float*)take((size_t)n * 64 * sizeof(float));
    float* pool    = (float*)take(64 * 64 * sizeof(float));

    init_kernel<<<(n + 256) / 256, 256, 0, stream>>>(offs, cursor, pool, n);
    detect_kernel<<<1, 256, 0, stream>>>((const int*)edge, flag, E);

    // CSR build (reused by all 3 layers)
    hist_kernel<<<(E + 255) / 256, 256, 0, stream>>>(edge, flag, offs, E, n);
    const int nbScan = (n + 2047) / 2048;
    scanA<<<nbScan, 256, 0, stream>>>(offs, blockSums, n);
    scanB<<<1, 256, 0, stream>>>(blockSums, nbScan);
    scanC<<<nbScan, 256, 0, stream>>>(offs, blockSums, n, E);
    scatter_kernel<<<(E + 255) / 256, 256, 0, stream>>>(edge, flag, offs, cursor, ss, E, n);

    const int nodeBlocks = (n + 3) / 4;
    // layer 1 lift
    mm_kernel<<<1024, 256, 0, stream>>>(x, W1l, W1r, b1, ZA, RA, n);
    // layer 1 agg fused with layer 2 lift
    aggmm_kernel<<<nodeBlocks, 256, 0, stream>>>(ZA, RA, offs, ss, W2l, W2r, b2, ZB, RB, n);
    // layer 2 agg fused with layer 3 lift
    aggmm_kernel<<<nodeBlocks, 256, 0, stream>>>(ZB, RB, offs, ss, W3l, W3r, b3, ZA, RA, n);
    // layer 3 agg
    agg_kernel<<<nodeBlocks, 256, 0, stream>>>(ZA, RA, offs, ss, H, n);

    // pool + head
    pool_kernel<<<(n + 1023) / 1024, 256, 0, stream>>>(H, batch, flag, pool, n);
    head_kernel<<<1, 256, 0, stream>>>(pool, batch, flag, Wc1, bc1, Wc2, bc2,
                                       (float*)d_out, n);
}